// Round 1
// baseline (306.007 us; speedup 1.0000x reference)
//
#include <hip/hip_runtime.h>
#include <math.h>

#define NN 512
#define WD 64
#define RH 4
#define OUTD 256
#define IND 256
#define IFACE_ 471
#define CDIM_ 727
#define TC 2181   // 3*CDIM
#define BS_ 64

// ---- output offsets (floats) ----
#define O_Y   0
#define O_MN  16384
#define O_UN  2113536
#define O_LN  2146304
#define O_WPN 18923520
#define O_WRN 18956288
#define O_WW  19087360
#define O_HC  19120128

// ---- workspace offsets (floats) ----
#define PART_STRIDE 618624   // per-z partial: [mx 279168 | mh 279168 | iface 60288]
#define MH_OFF  279168
#define IF_OFF  558336
#define WS_C    4948992      // c buffer 128*727
#define WS_PAR  5042048      // params 64*512
#define WS_FWD  5074816      // W_fwd 64*512*4
#define WS_BWD  5205888      // W_bwd 64*512*4 (zeroed, atomic target)
#define WS_LKR  5336960      // W_lookup_r 64*512*4

// ---- per-batch param layout (stride 512) ----
#define PK_NKW 0
#define PK_ER  64
#define PK_WV  128
#define PK_NKR 192
#define PK_BR  448
#define PK_MOD 452
#define PK_BW  464
#define PK_AG  465
#define PK_WG  466
#define PK_SUM 467
#define PK_FG  468

__device__ __forceinline__ float sigf(float x){ return 1.f/(1.f+expf(-x)); }
__device__ __forceinline__ float softplusf(float x){ return (x>20.f)? x : log1pf(expf(x)); }
__device__ __forceinline__ float geluf(float x){ return 0.5f*x*(1.f+erff(x*0.70710678118654752440f)); }
__device__ __forceinline__ float dot4(float4 a, float4 b){ return a.x*b.x+a.y*b.y+a.z*b.z+a.w*b.w; }

// ======================= generic fp32 tile GEMM body =======================
// C[m0:m0+32, n0:n0+128] = A[m0:.., k0:kend] @ B[k0:kend, n0:..]  (plain store)
__device__ __forceinline__ void gemm_tile_body(
    const float* __restrict__ A, int lda,
    const float* __restrict__ B, int ldb,
    float* __restrict__ C, int ldc, int Ncols,
    int k0, int kend, int m0, int n0, int t)
{
  __shared__ float As[32][36];
  __shared__ float Bs[32][132];
  float acc[4][4] = {{0.f}};
  int cg = t & 31;      // 32 col-groups of 4
  int rg = t >> 5;      // 8 row-groups of 4
  for (int kc = k0; kc < kend; kc += 32) {
    #pragma unroll
    for (int i = 0; i < 4; i++) {
      int idx = t + 256*i;
      int m = idx >> 5, kk = idx & 31;
      float v = 0.f;
      if (kc + kk < kend) v = A[(size_t)(m0+m)*lda + kc + kk];
      As[kk][m] = v;
    }
    #pragma unroll
    for (int i = 0; i < 16; i++) {
      int idx = t + 256*i;
      int kk = idx >> 7, c = idx & 127;
      float v = 0.f;
      if (kc + kk < kend && n0 + c < Ncols) v = B[(size_t)(kc+kk)*ldb + n0 + c];
      Bs[kk][c] = v;
    }
    __syncthreads();
    #pragma unroll
    for (int kk = 0; kk < 32; kk++) {
      float4 a4 = *(const float4*)&As[kk][rg*4];
      float4 b4 = *(const float4*)&Bs[kk][cg*4];
      acc[0][0]+=a4.x*b4.x; acc[0][1]+=a4.x*b4.y; acc[0][2]+=a4.x*b4.z; acc[0][3]+=a4.x*b4.w;
      acc[1][0]+=a4.y*b4.x; acc[1][1]+=a4.y*b4.y; acc[1][2]+=a4.y*b4.z; acc[1][3]+=a4.y*b4.w;
      acc[2][0]+=a4.z*b4.x; acc[2][1]+=a4.z*b4.y; acc[2][2]+=a4.z*b4.z; acc[2][3]+=a4.z*b4.w;
      acc[3][0]+=a4.w*b4.x; acc[3][1]+=a4.w*b4.y; acc[3][2]+=a4.w*b4.z; acc[3][3]+=a4.w*b4.w;
    }
    __syncthreads();
  }
  #pragma unroll
  for (int i = 0; i < 4; i++) {
    int m = m0 + rg*4 + i;
    int n = n0 + cg*4;
    if (n + 3 < Ncols) {
      float4 o; o.x=acc[i][0]; o.y=acc[i][1]; o.z=acc[i][2]; o.w=acc[i][3];
      *(float4*)&C[(size_t)m*ldc + n] = o;
    } else {
      for (int j = 0; j < 4; j++) if (n + j < Ncols) C[(size_t)m*ldc + n + j] = acc[i][j];
    }
  }
}

// z<8: mx part z (A=inputs 128x256, B=gru_kernel). z>=8: mh part z-8 (A=h 128x727, B=gru_rkernel)
__global__ __launch_bounds__(256) void k_gemm1(const float* __restrict__ xin,
    const float* __restrict__ hin, const float* __restrict__ gk,
    const float* __restrict__ grk, float* __restrict__ P)
{
  int z = blockIdx.z;
  int n0 = blockIdx.x * 128, m0 = blockIdx.y * 32;
  const float* A; const float* B; int lda, K, kch, zz; float* C;
  if (z < 8) { A = xin; lda = IND;  B = gk;  K = IND;  kch = 32; zz = z;
               C = P + (size_t)z*PART_STRIDE; }
  else       { A = hin; lda = CDIM_; B = grk; K = CDIM_; kch = 91; zz = z-8;
               C = P + (size_t)(z-8)*PART_STRIDE + MH_OFF; }
  int k0 = zz * kch;
  int kend = k0 + kch; if (kend > K) kend = K;
  gemm_tile_body(A, lda, B, TC, C, TC, TC, k0, kend, m0, n0, threadIdx.x);
}

__global__ __launch_bounds__(256) void k_gemm2(const float* __restrict__ cbuf,
    const float* __restrict__ Wif, float* __restrict__ P)
{
  int z = blockIdx.z;
  int k0 = z * 91;
  int kend = k0 + 91; if (kend > CDIM_) kend = CDIM_;
  gemm_tile_body(cbuf, CDIM_, Wif, IFACE_,
                 P + (size_t)z*PART_STRIDE + IF_OFF, IFACE_, IFACE_,
                 k0, kend, blockIdx.y*32, blockIdx.x*128, threadIdx.x);
}

// ======================= GRU pointwise =======================
__global__ __launch_bounds__(256) void k_gru(const float* __restrict__ P,
    const float* __restrict__ hprev, const float* __restrict__ gbias,
    float* __restrict__ cbuf, float* __restrict__ out_hc)
{
  int idx = blockIdx.x*256 + threadIdx.x;
  if (idx >= 128*CDIM_) return;
  int p = idx / CDIM_, u = idx % CDIM_;
  float mxz=0,mxr=0,mxh=0,mhz=0,mhr=0,mhh=0;
  #pragma unroll
  for (int z = 0; z < 8; z++) {
    const float* px = P + (size_t)z*PART_STRIDE + (size_t)p*TC;
    const float* ph = P + (size_t)z*PART_STRIDE + MH_OFF + (size_t)p*TC;
    mxz += px[u]; mxr += px[CDIM_+u]; mxh += px[2*CDIM_+u];
    mhz += ph[u]; mhr += ph[CDIM_+u]; mhh += ph[2*CDIM_+u];
  }
  mxz += gbias[u];      mxr += gbias[CDIM_+u];      mxh += gbias[2*CDIM_+u];
  mhz += gbias[TC+u];   mhr += gbias[TC+CDIM_+u];   mhh += gbias[TC+2*CDIM_+u];
  float z_ = sigf(mxz + mhz);
  float r_ = sigf(mxr + mhr);
  float hh = geluf(mxh + r_*mhh);
  float h  = hprev[(size_t)p*CDIM_ + u];
  float cv = z_*h + (1.f - z_)*hh;
  cbuf[(size_t)p*CDIM_ + u] = cv;
  out_hc[(size_t)p*CDIM_ + u] = cv;
}

// ======================= per-batch small ops =======================
__global__ __launch_bounds__(512) void k_small(
    const float* __restrict__ P, const float* __restrict__ M,
    const float* __restrict__ usage, const float* __restrict__ W_read,
    const float* __restrict__ W_write, float* __restrict__ out,
    float* __restrict__ params)
{
  __shared__ float ifr[IFACE_], ifw[IFACE_];
  __shared__ float su[512]; __shared__ int si[512];
  __shared__ float cp[512];
  __shared__ float alloc_l[512];
  __shared__ float red[512];
  __shared__ float s_nkw[64];
  __shared__ float s_fg[4];
  __shared__ float s_bw, s_ag, s_wg;
  int b = blockIdx.x, t = threadIdx.x;
  float* pp = params + b*512;

  // 1. reduce iface partials for both controller rows
  if (t < IFACE_) {
    float sr = 0.f, sw = 0.f;
    #pragma unroll
    for (int z = 0; z < 8; z++) {
      const float* base = P + (size_t)z*PART_STRIDE + IF_OFF;
      sr += base[(b*2+0)*IFACE_ + t];
      sw += base[(b*2+1)*IFACE_ + t];
    }
    ifr[t] = sr; ifw[t] = sw;
  }
  __syncthreads();

  // 2. activations / params
  if (t < 64) {
    float ss = 0.f;
    for (int w = 0; w < 64; w++) { float v = ifw[260+w]; ss += v*v; }
    float rn = rsqrtf(fmaxf(ss, 1e-12f));
    float nk = ifw[260+t]*rn;
    pp[PK_NKW + t] = nk; s_nkw[t] = nk;
    pp[PK_ER  + t] = sigf(ifw[325+t]);
    pp[PK_WV  + t] = ifw[389+t];
  } else if (t < 320) {
    int r = (t-64) >> 6, w = (t-64) & 63;
    float ss = 0.f;
    for (int w2 = 0; w2 < 64; w2++) { float v = ifr[r*64+w2]; ss += v*v; }
    pp[PK_NKR + r*64 + w] = ifr[r*64+w]*rsqrtf(fmaxf(ss, 1e-12f));
  } else if (t < 324) {
    pp[PK_BR + (t-320)] = 1.f + softplusf(ifr[256 + (t-320)]);
  } else if (t < 336) {
    int i = t-324; int mm = i >> 2, r = i & 3;
    float v0 = ifr[459+r], v1 = ifr[459+4+r], v2 = ifr[459+8+r];
    float mx = fmaxf(v0, fmaxf(v1, v2));
    float e0 = expf(v0-mx), e1 = expf(v1-mx), e2 = expf(v2-mx);
    float den = e0+e1+e2;
    pp[PK_MOD + i] = (mm==0 ? e0 : (mm==1 ? e1 : e2)) / den;
  } else if (t == 336) { float v = 1.f + softplusf(ifw[324]); pp[PK_BW] = v; s_bw = v; }
  else if (t == 337) { float v = sigf(ifw[457]); pp[PK_AG] = v; s_ag = v; }
  else if (t == 338) { float v = sigf(ifw[458]); pp[PK_WG] = v; s_wg = v; }
  else if (t < 343) { int r = t-339; float v = sigf(ifw[453+r]); pp[PK_FG+r] = v; s_fg[r] = v; }
  __syncthreads();

  // 3. usage_n
  {
    float4 wr4 = *(const float4*)&W_read[(size_t)(b*512+t)*4];
    float ret = (1.f - s_fg[0]*wr4.x)*(1.f - s_fg[1]*wr4.y)*(1.f - s_fg[2]*wr4.z)*(1.f - s_fg[3]*wr4.w);
    float u = usage[b*512+t], w = W_write[b*512+t];
    float un = (u + w - u*w)*ret;
    out[O_UN + b*512 + t] = un;
    su[t] = un; si[t] = t;
  }
  __syncthreads();

  // 4. bitonic sort ascending (usage, index)
  for (int k = 2; k <= 512; k <<= 1) {
    for (int j = k >> 1; j > 0; j >>= 1) {
      int ixj = t ^ j;
      if (ixj > t) {
        float a = su[t], c = su[ixj];
        int ia = si[t], ic = si[ixj];
        bool gt = (a > c) || (a == c && ia > ic);
        bool up = ((t & k) == 0);
        if (gt == up) { su[t] = c; su[ixj] = a; si[t] = ic; si[ixj] = ia; }
      }
      __syncthreads();
    }
  }

  // 5. inclusive product scan -> exclusive prefix -> W_alloc
  cp[t] = su[t]; __syncthreads();
  for (int off = 1; off < 512; off <<= 1) {
    float x = cp[t];
    float pfx = (t >= off) ? cp[t-off] : 1.f;
    __syncthreads();
    cp[t] = x * pfx;
    __syncthreads();
  }
  {
    float excl = (t > 0) ? cp[t-1] : 1.f;
    alloc_l[si[t]] = (1.f - su[t]) * excl;
  }
  __syncthreads();

  // 6. write content lookup (softmax over n)
  float mysim;
  {
    const float* mrow = M + (size_t)(b*512+t)*64;
    float ss = 0.f, dt = 0.f;
    #pragma unroll
    for (int i = 0; i < 16; i++) {
      float4 m4 = *(const float4*)&mrow[i*4];
      float4 k4 = *(const float4*)&s_nkw[i*4];
      ss += dot4(m4, m4); dt += dot4(m4, k4);
    }
    mysim = dt * rsqrtf(fmaxf(ss, 1e-12f)) * s_bw;
  }
  red[t] = mysim; __syncthreads();
  for (int s = 256; s > 0; s >>= 1) { if (t < s) red[t] = fmaxf(red[t], red[t+s]); __syncthreads(); }
  float mx = red[0]; __syncthreads();
  float e = expf(mysim - mx);
  red[t] = e; __syncthreads();
  for (int s = 256; s > 0; s >>= 1) { if (t < s) red[t] += red[t+s]; __syncthreads(); }
  float lkp = e / red[0];

  // 7. Ww + sum
  float ww = s_wg * (s_ag * alloc_l[t] + (1.f - s_ag) * lkp);
  out[O_WW + b*512 + t] = ww;
  __syncthreads();
  red[t] = ww; __syncthreads();
  for (int s = 256; s > 0; s >>= 1) { if (t < s) red[t] += red[t+s]; __syncthreads(); }
  if (t == 0) pp[PK_SUM] = red[0];
}

// ======================= M_n elementwise =======================
__global__ __launch_bounds__(256) void k_mn(const float* __restrict__ M,
    const float* __restrict__ params, float* __restrict__ out)
{
  int idx = blockIdx.x*256 + threadIdx.x;   // float4 units, 524288 total
  int w4 = idx & 15, n = (idx >> 4) & 511, b = idx >> 13;
  float ww = out[O_WW + b*512 + n];
  const float* pp = params + b*512;
  float4 er = *(const float4*)&pp[PK_ER + w4*4];
  float4 wv = *(const float4*)&pp[PK_WV + w4*4];
  float4 m4 = *(const float4*)&M[(size_t)idx*4];
  float4 r;
  r.x = m4.x*(1.f - ww*er.x) + ww*wv.x;
  r.y = m4.y*(1.f - ww*er.y) + ww*wv.y;
  r.z = m4.z*(1.f - ww*er.z) + ww*wv.z;
  r.w = m4.w*(1.f - ww*er.w) + ww*wv.w;
  *(float4*)&out[O_MN + (size_t)idx*4] = r;
}

// ======================= Wp_n =======================
__global__ __launch_bounds__(256) void k_wpn(const float* __restrict__ Wp,
    const float* __restrict__ params, float* __restrict__ out)
{
  int idx = blockIdx.x*256 + threadIdx.x;   // 32768
  int b = idx >> 9;
  float sw = params[b*512 + PK_SUM];
  float ww = out[O_WW + idx];
  out[O_WPN + idx] = (1.f - sw)*Wp[idx] + ww;
}

// ======================= read content lookup =======================
__global__ __launch_bounds__(512) void k_lookupr(const float* __restrict__ out,
    const float* __restrict__ params, float* __restrict__ lkr)
{
  __shared__ float nk[256];
  __shared__ float red[512];
  int b = blockIdx.x, t = threadIdx.x;
  const float* pp = params + b*512;
  if (t < 256) nk[t] = pp[PK_NKR + t];
  __syncthreads();
  const float* mrow = out + O_MN + (size_t)(b*512+t)*64;
  float ss = 0.f, d0 = 0.f, d1 = 0.f, d2 = 0.f, d3 = 0.f;
  #pragma unroll
  for (int i = 0; i < 16; i++) {
    float4 m4 = *(const float4*)&mrow[i*4];
    ss += dot4(m4, m4);
    d0 += dot4(m4, *(const float4*)&nk[      i*4]);
    d1 += dot4(m4, *(const float4*)&nk[ 64 + i*4]);
    d2 += dot4(m4, *(const float4*)&nk[128 + i*4]);
    d3 += dot4(m4, *(const float4*)&nk[192 + i*4]);
  }
  float rn = rsqrtf(fmaxf(ss, 1e-12f));
  float sim[4];
  sim[0] = d0*rn*pp[PK_BR+0]; sim[1] = d1*rn*pp[PK_BR+1];
  sim[2] = d2*rn*pp[PK_BR+2]; sim[3] = d3*rn*pp[PK_BR+3];
  float res[4];
  for (int r = 0; r < 4; r++) {
    red[t] = sim[r]; __syncthreads();
    for (int s = 256; s > 0; s >>= 1) { if (t < s) red[t] = fmaxf(red[t], red[t+s]); __syncthreads(); }
    float mx = red[0]; __syncthreads();
    float e = expf(sim[r] - mx);
    red[t] = e; __syncthreads();
    for (int s = 256; s > 0; s >>= 1) { if (t < s) red[t] += red[t+s]; __syncthreads(); }
    res[r] = e / red[0];
    __syncthreads();
  }
  float4 o; o.x = res[0]; o.y = res[1]; o.z = res[2]; o.w = res[3];
  *(float4*)&lkr[(size_t)(b*512+t)*4] = o;
}

// ======================= L_n + fused W_fwd / W_bwd =======================
__global__ __launch_bounds__(256) void k_ln(const float* __restrict__ L,
    const float* __restrict__ Wp, const float* __restrict__ W_read,
    float* __restrict__ out, float* __restrict__ fwd, float* __restrict__ bwd)
{
  __shared__ float T[64][68];
  __shared__ float wwl[512], wpl[512];
  __shared__ float wrT[4][516];
  __shared__ float bwdl[2048];
  __shared__ float4 red4[256];
  int b  = blockIdx.x >> 3;
  int i0 = (blockIdx.x & 7) * 64;
  int t  = threadIdx.x;
  for (int q = 0; q < 2; q++) {
    int n = t + q*256;
    wwl[n] = out[O_WW + b*512 + n];
    wpl[n] = Wp[b*512 + n];
    float4 w4 = *(const float4*)&W_read[(size_t)(b*512+n)*4];
    wrT[0][n] = w4.x; wrT[1][n] = w4.y; wrT[2][n] = w4.z; wrT[3][n] = w4.w;
  }
  #pragma unroll
  for (int q = 0; q < 8; q++) bwdl[t + q*256] = 0.f;
  __syncthreads();

  int fa = t >> 2, fr = t & 3;                     // fwd role
  int bc4 = t & 15, br = (t >> 4) & 3, bap = t >> 6; // bwd role
  float facc = 0.f;
  const float* Lb  = L + (size_t)b*512*512;
  float* LNb = out + O_LN + (size_t)b*512*512;

  for (int jt = 0; jt < 8; jt++) {
    int j0 = jt*64;
    #pragma unroll
    for (int q = 0; q < 4; q++) {
      int f = t + q*256;
      int a = f >> 4, c4 = f & 15;
      int gi = i0 + a, gj = j0 + c4*4;
      float4 l4 = *(const float4*)&Lb[(size_t)gi*512 + gj];
      float wwi = wwl[gi];
      float base = 1.f - wwi;
      float4 r;
      r.x = (base - wwl[gj+0])*l4.x + wwi*wpl[gj+0];
      r.y = (base - wwl[gj+1])*l4.y + wwi*wpl[gj+1];
      r.z = (base - wwl[gj+2])*l4.z + wwi*wpl[gj+2];
      r.w = (base - wwl[gj+3])*l4.w + wwi*wpl[gj+3];
      int d = gi - gj;
      if (d == 0) r.x = 0.f; else if (d == 1) r.y = 0.f;
      else if (d == 2) r.z = 0.f; else if (d == 3) r.w = 0.f;
      *(float4*)&LNb[(size_t)gi*512 + gj] = r;
      *(float4*)&T[a][c4*4] = r;
    }
    __syncthreads();
    // fwd: one scalar per (row, r)
    {
      const float* wrow = &wrT[fr][j0];
      #pragma unroll
      for (int c4 = 0; c4 < 16; c4++) {
        float4 t4 = *(const float4*)&T[fa][c4*4];
        float4 w4 = *(const float4*)&wrow[c4*4];
        facc += dot4(t4, w4);
      }
    }
    // bwd partial: float4 of columns per (c4, r, a-phase)
    {
      float4 bacc; bacc.x = bacc.y = bacc.z = bacc.w = 0.f;
      #pragma unroll
      for (int s = 0; s < 16; s++) {
        int a = bap*16 + s;
        float4 t4 = *(const float4*)&T[a][bc4*4];
        float w = wrT[br][i0 + a];
        bacc.x += t4.x*w; bacc.y += t4.y*w; bacc.z += t4.z*w; bacc.w += t4.w*w;
      }
      red4[t] = bacc;
    }
    __syncthreads();
    if (t < 64) {
      int c4 = t & 15, r = t >> 4;
      float4 s0 = red4[t], s1 = red4[t+64], s2 = red4[t+128], s3 = red4[t+192];
      float tx = s0.x+s1.x+s2.x+s3.x, ty = s0.y+s1.y+s2.y+s3.y;
      float tz = s0.z+s1.z+s2.z+s3.z, tw = s0.w+s1.w+s2.w+s3.w;
      int jb = j0 + c4*4;
      bwdl[(jb+0)*4 + r] += tx; bwdl[(jb+1)*4 + r] += ty;
      bwdl[(jb+2)*4 + r] += tz; bwdl[(jb+3)*4 + r] += tw;
    }
    __syncthreads();
  }
  fwd[(size_t)(b*512 + i0 + fa)*4 + fr] = facc;
  #pragma unroll
  for (int q = 0; q < 8; q++) {
    int idx = t + q*256;
    atomicAdd(&bwd[(size_t)b*2048 + idx], bwdl[idx]);
  }
}

// ======================= Wr_n, read_v, y =======================
__global__ __launch_bounds__(256) void k_final(const float* __restrict__ fwd,
    const float* __restrict__ bwd, const float* __restrict__ lkr,
    const float* __restrict__ params, const float* __restrict__ Wro,
    float* __restrict__ out)
{
  __shared__ float wrl[2048];
  __shared__ float rv[256];
  __shared__ float mo[12];
  int b = blockIdx.x, t = threadIdx.x;
  const float* pp = params + b*512;
  if (t < 12) mo[t] = pp[PK_MOD + t];
  __syncthreads();
  for (int q = 0; q < 2; q++) {
    int n = q*256 + t;
    size_t o = (size_t)(b*512 + n)*4;
    float4 f4 = *(const float4*)&fwd[o];
    float4 b4 = *(const float4*)&bwd[o];
    float4 l4 = *(const float4*)&lkr[o];
    float4 w;
    w.x = mo[0]*b4.x + mo[4]*l4.x + mo[8] *f4.x;
    w.y = mo[1]*b4.y + mo[5]*l4.y + mo[9] *f4.y;
    w.z = mo[2]*b4.z + mo[6]*l4.z + mo[10]*f4.z;
    w.w = mo[3]*b4.w + mo[7]*l4.w + mo[11]*f4.w;
    *(float4*)&out[O_WRN + o] = w;
    *(float4*)&wrl[n*4] = w;
  }
  __syncthreads();
  {
    int r = t >> 6, w = t & 63;
    float acc = 0.f;
    const float* mn = out + O_MN + (size_t)b*512*64;
    for (int n = 0; n < 512; n++) acc += wrl[n*4 + r] * mn[n*64 + w];
    rv[t] = acc;   // t == r*64 + w == flat k index
  }
  __syncthreads();
  {
    float acc = 0.f;
    for (int k = 0; k < 256; k++) acc += rv[k] * Wro[k*256 + t];
    out[O_Y + b*256 + t] = acc;
  }
}

// ======================= launch =======================
extern "C" void kernel_launch(void* const* d_in, const int* in_sizes, int n_in,
                              void* d_out, int out_size, void* d_ws, size_t ws_size,
                              hipStream_t stream)
{
  const float* inputs  = (const float*)d_in[0];
  const float* M       = (const float*)d_in[1];
  const float* usage   = (const float*)d_in[2];
  const float* L       = (const float*)d_in[3];
  const float* Wp      = (const float*)d_in[4];
  const float* W_read  = (const float*)d_in[5];
  const float* W_write = (const float*)d_in[6];
  const float* h_ctrl  = (const float*)d_in[7];
  const float* W_iface = (const float*)d_in[8];
  const float* W_ro    = (const float*)d_in[9];
  const float* gk      = (const float*)d_in[10];
  const float* grk     = (const float*)d_in[11];
  const float* gb      = (const float*)d_in[12];
  float* out = (float*)d_out;
  float* ws  = (float*)d_ws;

  // zero the atomic W_bwd accumulator
  hipMemsetAsync(ws + WS_BWD, 0, 131072*sizeof(float), stream);

  dim3 g1(18, 4, 16);
  k_gemm1<<<g1, 256, 0, stream>>>(inputs, h_ctrl, gk, grk, ws);
  k_gru<<<(128*CDIM_ + 255)/256, 256, 0, stream>>>(ws, h_ctrl, gb, ws + WS_C, out + O_HC);
  dim3 g2(4, 4, 8);
  k_gemm2<<<g2, 256, 0, stream>>>(ws + WS_C, W_iface, ws);
  k_small<<<64, 512, 0, stream>>>(ws, M, usage, W_read, W_write, out, ws + WS_PAR);
  k_mn<<<2048, 256, 0, stream>>>(M, ws + WS_PAR, out);
  k_wpn<<<128, 256, 0, stream>>>(Wp, ws + WS_PAR, out);
  k_lookupr<<<64, 512, 0, stream>>>(out, ws + WS_PAR, ws + WS_LKR);
  k_ln<<<512, 256, 0, stream>>>(L, Wp, W_read, out, ws + WS_FWD, ws + WS_BWD);
  k_final<<<64, 256, 0, stream>>>(ws + WS_FWD, ws + WS_BWD, ws + WS_LKR, ws + WS_PAR, W_ro, out);
}

// Round 2
// 292.717 us; speedup vs baseline: 1.0454x; 1.0454x over previous
//
#include <hip/hip_runtime.h>
#include <math.h>

#define NN 512
#define WD 64
#define RH 4
#define OUTD 256
#define IND 256
#define IFACE_ 471
#define CDIM_ 727
#define TC 2181   // 3*CDIM
#define BS_ 64

// ---- output offsets (floats) ----
#define O_Y   0
#define O_MN  16384
#define O_UN  2113536
#define O_LN  2146304
#define O_WPN 18923520
#define O_WRN 18956288
#define O_WW  19087360
#define O_HC  19120128

// ---- workspace offsets (floats) ----
#define PART_STRIDE 618624   // per-z partial: [mx 279168 | mh 279168 | iface 60288]
#define MH_OFF  279168
#define IF_OFF  558336
#define WS_C    4948992      // c buffer 128*727
#define WS_PAR  5042048      // params 64*512
#define WS_FWD  5074816      // W_fwd 64*512*4
#define WS_BWD  5205888      // W_bwd 64*512*4 (zeroed, atomic target)
#define WS_SIM  5336960      // sims 64*512*4

// ---- per-batch param layout (stride 512) ----
#define PK_NKW 0
#define PK_ER  64
#define PK_WV  128
#define PK_NKR 192
#define PK_BR  448
#define PK_MOD 452
#define PK_BW  464
#define PK_AG  465
#define PK_WG  466
#define PK_FG  468

__device__ __forceinline__ float sigf(float x){ return 1.f/(1.f+expf(-x)); }
__device__ __forceinline__ float softplusf(float x){ return (x>20.f)? x : log1pf(expf(x)); }
__device__ __forceinline__ float geluf(float x){ return 0.5f*x*(1.f+erff(x*0.70710678118654752440f)); }
__device__ __forceinline__ float dot4(float4 a, float4 b){ return a.x*b.x+a.y*b.y+a.z*b.z+a.w*b.w; }
__device__ __forceinline__ void fma4(float4& a, float s, float4 v){ a.x+=s*v.x; a.y+=s*v.y; a.z+=s*v.z; a.w+=s*v.w; }
__device__ __forceinline__ float4 ln_combine(float4 l4, float4 wwj, float4 wpj, float base, float wwi){
  float4 r;
  r.x = (base - wwj.x)*l4.x + wwi*wpj.x;
  r.y = (base - wwj.y)*l4.y + wwi*wpj.y;
  r.z = (base - wwj.z)*l4.z + wwi*wpj.z;
  r.w = (base - wwj.w)*l4.w + wwi*wpj.w;
  return r;
}
__device__ __forceinline__ void diag_zero(float4& r, int d){
  if (d==0) r.x=0.f; else if (d==1) r.y=0.f; else if (d==2) r.z=0.f; else if (d==3) r.w=0.f;
}

// ======================= 64x128 fp32 tile GEMM body =======================
__device__ __forceinline__ void gemm_tile64(
    const float* __restrict__ A, int lda,
    const float* __restrict__ B, int ldb,
    float* __restrict__ C, int ldc, int Ncols,
    int k0, int kend, int m0, int n0, int t)
{
  __shared__ float As[32][68];
  __shared__ float Bs[32][132];
  float acc[8][4] = {{0.f}};
  int cg = t & 31;      // 32 col-groups of 4
  int rg = t >> 5;      // 8 row-groups of 4 (x2 halves)
  for (int kc = k0; kc < kend; kc += 32) {
    #pragma unroll
    for (int i = 0; i < 8; i++) {
      int idx = t + 256*i;
      int m = idx >> 5, kk = idx & 31;
      float v = 0.f;
      if (kc + kk < kend) v = A[(size_t)(m0+m)*lda + kc + kk];
      As[kk][m] = v;
    }
    #pragma unroll
    for (int i = 0; i < 16; i++) {
      int idx = t + 256*i;
      int kk = idx >> 7, c = idx & 127;
      float v = 0.f;
      if (kc + kk < kend && n0 + c < Ncols) v = B[(size_t)(kc+kk)*ldb + n0 + c];
      Bs[kk][c] = v;
    }
    __syncthreads();
    #pragma unroll
    for (int kk = 0; kk < 32; kk++) {
      float4 alo = *(const float4*)&As[kk][rg*4];
      float4 ahi = *(const float4*)&As[kk][32 + rg*4];
      float4 b4  = *(const float4*)&Bs[kk][cg*4];
      float av[8] = {alo.x, alo.y, alo.z, alo.w, ahi.x, ahi.y, ahi.z, ahi.w};
      float bv[4] = {b4.x, b4.y, b4.z, b4.w};
      #pragma unroll
      for (int i = 0; i < 8; i++)
        #pragma unroll
        for (int j = 0; j < 4; j++)
          acc[i][j] += av[i]*bv[j];
    }
    __syncthreads();
  }
  #pragma unroll
  for (int i = 0; i < 8; i++) {
    int mrow = (i < 4) ? (rg*4 + i) : (32 + rg*4 + (i-4));
    int m = m0 + mrow;
    int n = n0 + cg*4;
    if (n + 3 < Ncols) {
      float4 o; o.x=acc[i][0]; o.y=acc[i][1]; o.z=acc[i][2]; o.w=acc[i][3];
      *(float4*)&C[(size_t)m*ldc + n] = o;
    } else {
      for (int j = 0; j < 4; j++) if (n + j < Ncols) C[(size_t)m*ldc + n + j] = acc[i][j];
    }
  }
}

// z<8: mx part z (A=inputs 128x256). z>=8: mh part z-8 (A=h 128x727)
__global__ __launch_bounds__(256) void k_gemm1(const float* __restrict__ xin,
    const float* __restrict__ hin, const float* __restrict__ gk,
    const float* __restrict__ grk, float* __restrict__ P)
{
  int z = blockIdx.z;
  int n0 = blockIdx.x * 128, m0 = blockIdx.y * 64;
  const float* A; const float* B; int lda, K, kch, zz; float* C;
  if (z < 8) { A = xin; lda = IND;  B = gk;  K = IND;  kch = 32; zz = z;
               C = P + (size_t)z*PART_STRIDE; }
  else       { A = hin; lda = CDIM_; B = grk; K = CDIM_; kch = 91; zz = z-8;
               C = P + (size_t)(z-8)*PART_STRIDE + MH_OFF; }
  int k0 = zz * kch;
  int kend = k0 + kch; if (kend > K) kend = K;
  gemm_tile64(A, lda, B, TC, C, TC, TC, k0, kend, m0, n0, threadIdx.x);
}

__global__ __launch_bounds__(256) void k_gemm2(const float* __restrict__ cbuf,
    const float* __restrict__ Wif, float* __restrict__ P)
{
  int z = blockIdx.z;
  int k0 = z * 91;
  int kend = k0 + 91; if (kend > CDIM_) kend = CDIM_;
  gemm_tile64(cbuf, CDIM_, Wif, IFACE_,
              P + (size_t)z*PART_STRIDE + IF_OFF, IFACE_, IFACE_,
              k0, kend, blockIdx.y*64, blockIdx.x*128, threadIdx.x);
}

// ======================= GRU pointwise =======================
__global__ __launch_bounds__(256) void k_gru(const float* __restrict__ P,
    const float* __restrict__ hprev, const float* __restrict__ gbias,
    float* __restrict__ cbuf, float* __restrict__ out_hc)
{
  int idx = blockIdx.x*256 + threadIdx.x;
  if (idx >= 128*CDIM_) return;
  int p = idx / CDIM_, u = idx % CDIM_;
  float mxz=0,mxr=0,mxh=0,mhz=0,mhr=0,mhh=0;
  #pragma unroll
  for (int z = 0; z < 8; z++) {
    const float* px = P + (size_t)z*PART_STRIDE + (size_t)p*TC;
    const float* ph = P + (size_t)z*PART_STRIDE + MH_OFF + (size_t)p*TC;
    mxz += px[u]; mxr += px[CDIM_+u]; mxh += px[2*CDIM_+u];
    mhz += ph[u]; mhr += ph[CDIM_+u]; mhh += ph[2*CDIM_+u];
  }
  mxz += gbias[u];      mxr += gbias[CDIM_+u];      mxh += gbias[2*CDIM_+u];
  mhz += gbias[TC+u];   mhr += gbias[TC+CDIM_+u];   mhh += gbias[TC+2*CDIM_+u];
  float z_ = sigf(mxz + mhz);
  float r_ = sigf(mxr + mhr);
  float hh = geluf(mxh + r_*mhh);
  float h  = hprev[(size_t)p*CDIM_ + u];
  float cv = z_*h + (1.f - z_)*hh;
  cbuf[(size_t)p*CDIM_ + u] = cv;
  out_hc[(size_t)p*CDIM_ + u] = cv;
}

// ======================= per-batch small ops =======================
__global__ __launch_bounds__(512) void k_small(
    const float* __restrict__ P, const float* __restrict__ M,
    const float* __restrict__ usage, const float* __restrict__ W_read,
    const float* __restrict__ W_write, const float* __restrict__ Wp,
    float* __restrict__ out, float* __restrict__ params)
{
  __shared__ float ifr[IFACE_], ifw[IFACE_];
  __shared__ float su[512]; __shared__ int si[512];
  __shared__ float alloc_l[512];
  __shared__ float s_nkw[64];
  __shared__ float s_fg[4];
  __shared__ float s_bw, s_ag, s_wg;
  __shared__ float wredA[8], wredB[8], warpTot[8];
  int b = blockIdx.x, t = threadIdx.x;
  int lane = t & 63, wid = t >> 6;
  float* pp = params + b*512;

  // 1. reduce iface partials for both controller rows
  if (t < IFACE_) {
    float sr = 0.f, sw = 0.f;
    #pragma unroll
    for (int z = 0; z < 8; z++) {
      const float* base = P + (size_t)z*PART_STRIDE + IF_OFF;
      sr += base[(b*2+0)*IFACE_ + t];
      sw += base[(b*2+1)*IFACE_ + t];
    }
    ifr[t] = sr; ifw[t] = sw;
  }
  __syncthreads();

  // 2. activations / params
  if (t < 64) {
    float ss = 0.f;
    for (int w = 0; w < 64; w++) { float v = ifw[260+w]; ss += v*v; }
    float rn = rsqrtf(fmaxf(ss, 1e-12f));
    float nk = ifw[260+t]*rn;
    pp[PK_NKW + t] = nk; s_nkw[t] = nk;
    pp[PK_ER  + t] = sigf(ifw[325+t]);
    pp[PK_WV  + t] = ifw[389+t];
  } else if (t < 320) {
    int r = (t-64) >> 6, w = (t-64) & 63;
    float ss = 0.f;
    for (int w2 = 0; w2 < 64; w2++) { float v = ifr[r*64+w2]; ss += v*v; }
    pp[PK_NKR + r*64 + w] = ifr[r*64+w]*rsqrtf(fmaxf(ss, 1e-12f));
  } else if (t < 324) {
    pp[PK_BR + (t-320)] = 1.f + softplusf(ifr[256 + (t-320)]);
  } else if (t < 336) {
    int i = t-324; int mm = i >> 2, r = i & 3;
    float v0 = ifr[459+r], v1 = ifr[459+4+r], v2 = ifr[459+8+r];
    float mx = fmaxf(v0, fmaxf(v1, v2));
    float e0 = expf(v0-mx), e1 = expf(v1-mx), e2 = expf(v2-mx);
    float den = e0+e1+e2;
    pp[PK_MOD + i] = (mm==0 ? e0 : (mm==1 ? e1 : e2)) / den;
  } else if (t == 336) { float v = 1.f + softplusf(ifw[324]); pp[PK_BW] = v; s_bw = v; }
  else if (t == 337) { float v = sigf(ifw[457]); pp[PK_AG] = v; s_ag = v; }
  else if (t == 338) { float v = sigf(ifw[458]); pp[PK_WG] = v; s_wg = v; }
  else if (t < 343) { int r = t-339; float v = sigf(ifw[453+r]); pp[PK_FG+r] = v; s_fg[r] = v; }
  __syncthreads();

  // 3. usage_n (registers)
  float un;
  {
    float4 wr4 = *(const float4*)&W_read[(size_t)(b*512+t)*4];
    float ret = (1.f - s_fg[0]*wr4.x)*(1.f - s_fg[1]*wr4.y)*(1.f - s_fg[2]*wr4.z)*(1.f - s_fg[3]*wr4.w);
    float u = usage[b*512+t], w = W_write[b*512+t];
    un = (u + w - u*w)*ret;
    out[O_UN + b*512 + t] = un;
  }

  // 4. hybrid bitonic sort ascending (value, index) — shuffle for j<64, LDS for j>=64
  float v = un; int key = t;
  for (int k = 2; k <= 512; k <<= 1) {
    for (int j = k >> 1; j > 0; j >>= 1) {
      bool dir = ((t & k) == 0);
      if (j >= 64) {
        su[t] = v; si[t] = key;
        __syncthreads();
        float pv = su[t ^ j]; int pi = si[t ^ j];
        bool gt = (v > pv) || (v == pv && key > pi);
        bool take = ((t & j) == 0) ? (gt == dir) : (gt != dir);
        if (take) { v = pv; key = pi; }
        __syncthreads();
      } else {
        float pv = __shfl_xor(v, j);
        int   pi = __shfl_xor(key, j);
        bool gt = (v > pv) || (v == pv && key > pi);
        bool take = ((t & j) == 0) ? (gt == dir) : (gt != dir);
        if (take) { v = pv; key = pi; }
      }
    }
  }

  // 5. cumprod scan (shuffle) -> exclusive -> W_alloc scatter
  {
    float x = v;
    #pragma unroll
    for (int off = 1; off < 64; off <<= 1) {
      float y = __shfl_up(x, off);
      if (lane >= off) x *= y;
    }
    if (lane == 63) warpTot[wid] = x;
    __syncthreads();
    float pre = 1.f;
    for (int w2 = 0; w2 < wid; w2++) pre *= warpTot[w2];
    float xm1 = __shfl_up(x, 1);
    float excl = (lane == 0) ? pre : pre*xm1;
    alloc_l[key] = (1.f - v)*excl;
  }
  __syncthreads();

  // 6. write content lookup softmax (shuffle reductions)
  float mysim;
  {
    const float* mrow = M + (size_t)(b*512+t)*64;
    float ss = 0.f, dt = 0.f;
    #pragma unroll
    for (int i = 0; i < 16; i++) {
      float4 m4 = *(const float4*)&mrow[i*4];
      float4 k4 = *(const float4*)&s_nkw[i*4];
      ss += dot4(m4, m4); dt += dot4(m4, k4);
    }
    mysim = dt * rsqrtf(fmaxf(ss, 1e-12f)) * s_bw;
  }
  float mw = mysim;
  #pragma unroll
  for (int off = 32; off > 0; off >>= 1) mw = fmaxf(mw, __shfl_xor(mw, off));
  if (lane == 0) wredA[wid] = mw;
  __syncthreads();
  float mx = wredA[0];
  #pragma unroll
  for (int i = 1; i < 8; i++) mx = fmaxf(mx, wredA[i]);
  float e = expf(mysim - mx);
  float sw_ = e;
  #pragma unroll
  for (int off = 32; off > 0; off >>= 1) sw_ += __shfl_xor(sw_, off);
  if (lane == 0) wredB[wid] = sw_;
  __syncthreads();
  float den = 0.f;
  #pragma unroll
  for (int i = 0; i < 8; i++) den += wredB[i];
  float lkp = e / den;

  // 7. Ww + sum
  float ww = s_wg * (s_ag * alloc_l[t] + (1.f - s_ag) * lkp);
  out[O_WW + b*512 + t] = ww;
  float wsum = ww;
  #pragma unroll
  for (int off = 32; off > 0; off >>= 1) wsum += __shfl_xor(wsum, off);
  if (lane == 0) wredA[wid] = wsum;
  __syncthreads();
  float sum = 0.f;
  #pragma unroll
  for (int i = 0; i < 8; i++) sum += wredA[i];

  // 8. Wp_n (merged)
  out[O_WPN + b*512 + t] = (1.f - sum)*Wp[b*512+t] + ww;
}

// ======================= M_n elementwise + read-lookup sims =======================
__global__ __launch_bounds__(256) void k_mn(const float* __restrict__ M,
    const float* __restrict__ params, float* __restrict__ out,
    float* __restrict__ sims)
{
  int t = threadIdx.x;
  int idx = blockIdx.x*256 + t;   // float4 units, 524288 total
  int w4 = idx & 15, n = (idx >> 4) & 511, b = idx >> 13;
  float ww = out[O_WW + b*512 + n];
  const float* pp = params + b*512;
  float4 er = *(const float4*)&pp[PK_ER + w4*4];
  float4 wv = *(const float4*)&pp[PK_WV + w4*4];
  float4 m4 = *(const float4*)&M[(size_t)idx*4];
  float4 r;
  r.x = m4.x*(1.f - ww*er.x) + ww*wv.x;
  r.y = m4.y*(1.f - ww*er.y) + ww*wv.y;
  r.z = m4.z*(1.f - ww*er.z) + ww*wv.z;
  r.w = m4.w*(1.f - ww*er.w) + ww*wv.w;
  *(float4*)&out[O_MN + (size_t)idx*4] = r;
  // sims: row norm + 4 key dots, reduced over the 16-lane row group
  float4 nk0 = *(const float4*)&pp[PK_NKR +       w4*4];
  float4 nk1 = *(const float4*)&pp[PK_NKR +  64 + w4*4];
  float4 nk2 = *(const float4*)&pp[PK_NKR + 128 + w4*4];
  float4 nk3 = *(const float4*)&pp[PK_NKR + 192 + w4*4];
  float ss = dot4(r, r);
  float d0 = dot4(r, nk0), d1 = dot4(r, nk1), d2 = dot4(r, nk2), d3 = dot4(r, nk3);
  #pragma unroll
  for (int m = 1; m < 16; m <<= 1) {
    ss += __shfl_xor(ss, m);
    d0 += __shfl_xor(d0, m); d1 += __shfl_xor(d1, m);
    d2 += __shfl_xor(d2, m); d3 += __shfl_xor(d3, m);
  }
  if ((t & 15) == 0) {
    float rn = rsqrtf(fmaxf(ss, 1e-12f));
    float4 s;
    s.x = d0*rn*pp[PK_BR+0]; s.y = d1*rn*pp[PK_BR+1];
    s.z = d2*rn*pp[PK_BR+2]; s.w = d3*rn*pp[PK_BR+3];
    *(float4*)&sims[(size_t)(b*512+n)*4] = s;
  }
}

// ======================= L_n + fused W_fwd / W_bwd (wave-per-row) =======================
__global__ __launch_bounds__(256) void k_ln(const float* __restrict__ L,
    const float* __restrict__ Wp, const float* __restrict__ W_read,
    float* __restrict__ out, float* __restrict__ fwd, float* __restrict__ bwd)
{
  __shared__ float wwl[512], wpl[512];
  __shared__ float wrT[4][512];
  __shared__ float wbuf[4][2048];
  int b  = blockIdx.x >> 3;
  int i0 = (blockIdx.x & 7) * 64;
  int t = threadIdx.x, lane = t & 63, wid = t >> 6;
  for (int q = 0; q < 2; q++) {
    int n = t + q*256;
    wwl[n] = out[O_WW + b*512 + n];
    wpl[n] = Wp[b*512 + n];
    float4 w4 = *(const float4*)&W_read[(size_t)(b*512+n)*4];
    wrT[0][n] = w4.x; wrT[1][n] = w4.y; wrT[2][n] = w4.z; wrT[3][n] = w4.w;
  }
  __syncthreads();
  int j0 = lane*4, j1 = 256 + lane*4;
  float4 ww0 = *(const float4*)&wwl[j0], ww1 = *(const float4*)&wwl[j1];
  float4 wp0 = *(const float4*)&wpl[j0], wp1 = *(const float4*)&wpl[j1];
  float4 wr0[4], wr1[4], b0[4], b1[4];
  #pragma unroll
  for (int rr = 0; rr < 4; rr++) {
    wr0[rr] = *(const float4*)&wrT[rr][j0];
    wr1[rr] = *(const float4*)&wrT[rr][j1];
    b0[rr] = make_float4(0.f,0.f,0.f,0.f);
    b1[rr] = make_float4(0.f,0.f,0.f,0.f);
  }
  const float* Lb  = L + (size_t)b*262144;
  float* LNb = out + O_LN + (size_t)b*262144;
  #pragma unroll 2
  for (int ri = 0; ri < 16; ri++) {
    int gi = i0 + ri*4 + wid;
    float wwi = wwl[gi], base = 1.f - wwi;
    float wi0 = wrT[0][gi], wi1 = wrT[1][gi], wi2 = wrT[2][gi], wi3 = wrT[3][gi];
    const float* lrow = Lb + (size_t)gi*512;
    float* orow = LNb + (size_t)gi*512;
    float4 l0 = *(const float4*)&lrow[j0];
    float4 l1 = *(const float4*)&lrow[j1];
    float4 r0 = ln_combine(l0, ww0, wp0, base, wwi);
    diag_zero(r0, gi - j0);
    float4 r1 = ln_combine(l1, ww1, wp1, base, wwi);
    diag_zero(r1, gi - j1);
    *(float4*)&orow[j0] = r0;
    *(float4*)&orow[j1] = r1;
    float f0 = dot4(r0, wr0[0]) + dot4(r1, wr1[0]);
    float f1 = dot4(r0, wr0[1]) + dot4(r1, wr1[1]);
    float f2 = dot4(r0, wr0[2]) + dot4(r1, wr1[2]);
    float f3 = dot4(r0, wr0[3]) + dot4(r1, wr1[3]);
    fma4(b0[0], wi0, r0); fma4(b0[1], wi1, r0); fma4(b0[2], wi2, r0); fma4(b0[3], wi3, r0);
    fma4(b1[0], wi0, r1); fma4(b1[1], wi1, r1); fma4(b1[2], wi2, r1); fma4(b1[3], wi3, r1);
    #pragma unroll
    for (int off = 32; off > 0; off >>= 1) {
      f0 += __shfl_xor(f0, off);
      f1 += __shfl_xor(f1, off);
      f2 += __shfl_xor(f2, off);
      f3 += __shfl_xor(f3, off);
    }
    if (lane == 0) {
      float4 o; o.x = f0; o.y = f1; o.z = f2; o.w = f3;
      *(float4*)&fwd[(size_t)(b*512+gi)*4] = o;
    }
  }
  // stage per-wave bwd partials, cross-wave reduce, one atomic pass
  #pragma unroll
  for (int rr = 0; rr < 4; rr++) {
    *(float4*)&wbuf[wid][       rr*256 + j0] = b0[rr];
    *(float4*)&wbuf[wid][1024 + rr*256 + j0] = b1[rr];
  }
  __syncthreads();
  #pragma unroll
  for (int k = 0; k < 8; k++) {
    int o = t + k*256;            // flat j*4+rr
    int j = o >> 2, rr = o & 3;
    int a = (j >> 8)*1024 + rr*256 + (j & 255);
    float s = wbuf[0][a] + wbuf[1][a] + wbuf[2][a] + wbuf[3][a];
    atomicAdd(&bwd[(size_t)b*2048 + o], s);
  }
}

// ======================= lookup softmax + Wr_n + read_v + y =======================
__global__ __launch_bounds__(1024) void k_final(const float* __restrict__ fwd,
    const float* __restrict__ bwd, const float* __restrict__ sims,
    const float* __restrict__ params, const float* __restrict__ Wro,
    float* __restrict__ out)
{
  __shared__ float wrl[2048];
  __shared__ float buf[1024];
  __shared__ float rv[256];
  __shared__ float mo[12];
  __shared__ float4 redm[8], reds[8];
  int b = blockIdx.x, t = threadIdx.x;
  int lane = t & 63, wid = t >> 6;
  const float* pp = params + b*512;
  if (t < 12) mo[t] = pp[PK_MOD + t];

  // Phase A: softmax over n (4 r at once), Wr_n
  float4 s4 = make_float4(0.f,0.f,0.f,0.f);
  if (t < 512) {
    s4 = *(const float4*)&sims[(size_t)(b*512+t)*4];
    float4 m4 = s4;
    #pragma unroll
    for (int off = 32; off > 0; off >>= 1) {
      m4.x = fmaxf(m4.x, __shfl_xor(m4.x, off));
      m4.y = fmaxf(m4.y, __shfl_xor(m4.y, off));
      m4.z = fmaxf(m4.z, __shfl_xor(m4.z, off));
      m4.w = fmaxf(m4.w, __shfl_xor(m4.w, off));
    }
    if (lane == 0) redm[wid] = m4;
  }
  __syncthreads();
  float4 e4 = make_float4(0.f,0.f,0.f,0.f);
  if (t < 512) {
    float4 mx = redm[0];
    #pragma unroll
    for (int i = 1; i < 8; i++) {
      mx.x = fmaxf(mx.x, redm[i].x); mx.y = fmaxf(mx.y, redm[i].y);
      mx.z = fmaxf(mx.z, redm[i].z); mx.w = fmaxf(mx.w, redm[i].w);
    }
    e4.x = expf(s4.x - mx.x); e4.y = expf(s4.y - mx.y);
    e4.z = expf(s4.z - mx.z); e4.w = expf(s4.w - mx.w);
    float4 t4 = e4;
    #pragma unroll
    for (int off = 32; off > 0; off >>= 1) {
      t4.x += __shfl_xor(t4.x, off); t4.y += __shfl_xor(t4.y, off);
      t4.z += __shfl_xor(t4.z, off); t4.w += __shfl_xor(t4.w, off);
    }
    if (lane == 0) reds[wid] = t4;
  }
  __syncthreads();
  if (t < 512) {
    float4 dn = reds[0];
    #pragma unroll
    for (int i = 1; i < 8; i++) { dn.x += reds[i].x; dn.y += reds[i].y; dn.z += reds[i].z; dn.w += reds[i].w; }
    float4 lk; lk.x = e4.x/dn.x; lk.y = e4.y/dn.y; lk.z = e4.z/dn.z; lk.w = e4.w/dn.w;
    size_t o = (size_t)(b*512 + t)*4;
    float4 f4 = *(const float4*)&fwd[o];
    float4 b4 = *(const float4*)&bwd[o];
    float4 w;
    w.x = mo[0]*b4.x + mo[4]*lk.x + mo[8] *f4.x;
    w.y = mo[1]*b4.y + mo[5]*lk.y + mo[9] *f4.y;
    w.z = mo[2]*b4.z + mo[6]*lk.z + mo[10]*f4.z;
    w.w = mo[3]*b4.w + mo[7]*lk.w + mo[11]*f4.w;
    *(float4*)&out[O_WRN + o] = w;
    *(float4*)&wrl[t*4] = w;
  }
  __syncthreads();

  // Phase B: read_v (4-way n-split)
  {
    int w = lane, r = wid & 3, n4 = t >> 8;
    const float* mnb = out + O_MN + (size_t)b*32768 + w;
    float acc = 0.f;
    int nb = n4*128;
    #pragma unroll 4
    for (int n = nb; n < nb + 128; n++) acc += wrl[n*4 + r] * mnb[(size_t)n*64];
    buf[t] = acc;
  }
  __syncthreads();
  if (t < 256) rv[t] = buf[t] + buf[t+256] + buf[t+512] + buf[t+768];
  __syncthreads();

  // Phase C: y (4-way k-split)
  {
    int o = t & 255, k4 = t >> 8;
    float acc = 0.f;
    #pragma unroll 4
    for (int k = k4*64; k < k4*64 + 64; k++) acc += rv[k] * Wro[k*256 + o];
    buf[t] = acc;
  }
  __syncthreads();
  if (t < 256) out[O_Y + b*256 + t] = buf[t] + buf[t+256] + buf[t+512] + buf[t+768];
}

// ======================= launch =======================
extern "C" void kernel_launch(void* const* d_in, const int* in_sizes, int n_in,
                              void* d_out, int out_size, void* d_ws, size_t ws_size,
                              hipStream_t stream)
{
  const float* inputs  = (const float*)d_in[0];
  const float* M       = (const float*)d_in[1];
  const float* usage   = (const float*)d_in[2];
  const float* L       = (const float*)d_in[3];
  const float* Wp      = (const float*)d_in[4];
  const float* W_read  = (const float*)d_in[5];
  const float* W_write = (const float*)d_in[6];
  const float* h_ctrl  = (const float*)d_in[7];
  const float* W_iface = (const float*)d_in[8];
  const float* W_ro    = (const float*)d_in[9];
  const float* gk      = (const float*)d_in[10];
  const float* grk     = (const float*)d_in[11];
  const float* gb      = (const float*)d_in[12];
  float* out = (float*)d_out;
  float* ws  = (float*)d_ws;

  hipMemsetAsync(ws + WS_BWD, 0, 131072*sizeof(float), stream);

  dim3 g1(18, 2, 16);
  k_gemm1<<<g1, 256, 0, stream>>>(inputs, h_ctrl, gk, grk, ws);
  k_gru<<<(128*CDIM_ + 255)/256, 256, 0, stream>>>(ws, h_ctrl, gb, ws + WS_C, out + O_HC);
  dim3 g2(4, 2, 8);
  k_gemm2<<<g2, 256, 0, stream>>>(ws + WS_C, W_iface, ws);
  k_small<<<64, 512, 0, stream>>>(ws, M, usage, W_read, W_write, Wp, out, ws + WS_PAR);
  k_mn<<<2048, 256, 0, stream>>>(M, ws + WS_PAR, out, ws + WS_SIM);
  k_ln<<<512, 256, 0, stream>>>(L, Wp, W_read, out, ws + WS_FWD, ws + WS_BWD);
  k_final<<<64, 1024, 0, stream>>>(ws + WS_FWD, ws + WS_BWD, ws + WS_SIM, ws + WS_PAR, W_ro, out);
}